// Round 14
// baseline (301.677 us; speedup 1.0000x reference)
//
#include <hip/hip_runtime.h>
#include <hip/hip_bf16.h>

typedef __attribute__((ext_vector_type(8))) short short8;
typedef __attribute__((ext_vector_type(4))) float f32x4;

#define MFMA16(a, b, c) __builtin_amdgcn_mfma_f32_16x16x32_bf16((a), (b), (c), 0, 0, 0)

__device__ __forceinline__ unsigned short f2bf(float x) {
    union { float f; unsigned int u; } v; v.f = x;
    unsigned int u = v.u;
    return (unsigned short)((u + 0x7FFFu + ((u >> 16) & 1u)) >> 16);
}

__device__ __forceinline__ float pow14(float x) {
    return exp2f(1.4f * log2f(x));
}

__device__ __forceinline__ short8 ld8(const unsigned short* p) {
    return *reinterpret_cast<const short8*>(p);
}

__device__ __forceinline__ void gld16(const void* src, const unsigned char* dst) {
    __builtin_amdgcn_global_load_lds(
        (const __attribute__((address_space(1))) void*)src,
        (__attribute__((address_space(3))) void*)dst, 16, 0, 0);
}

// ---- K0: bbn fp32 -> bf16 (plain + row-swizzled copy), row sums s[i] ---------
__global__ void k_prep_bbn(const float* __restrict__ bbn, unsigned short* __restrict__ bbn_h,
                           unsigned short* __restrict__ bbn_swz, float* __restrict__ s) {
    int row = blockIdx.x * 4 + (threadIdx.x >> 6);
    int lane = threadIdx.x & 63;
    float x = bbn[row * 64 + lane];
    unsigned short h = f2bf(x);
    bbn_h[row * 64 + lane] = h;
    bbn_swz[row * 64 + (lane ^ ((row & 7) << 3))] = h;
    float v = x;
    #pragma unroll
    for (int m = 1; m < 64; m <<= 1) v += __shfl_xor(v, m);
    if (lane == 0) s[row] = v;
}

__global__ void k_zero_d(float* __restrict__ dd) {
    dd[blockIdx.x * 1024 + threadIdx.x] = 0.f;
}

// ---- K0b/K2: transpose (+optional rsqrt(d) row scale, optional swizzle) ------
__global__ void k_transpose_scale(const float* __restrict__ in, unsigned short* __restrict__ out,
                                  const float* __restrict__ dvec, int K, int N, int swz) {
    __shared__ float tile[64][65];
    int tiles_k = K >> 6;
    int tk = blockIdx.x % tiles_k, tn = blockIdx.x / tiles_k;
    int k0 = tk * 64, n0 = tn * 64;
    int c = threadIdx.x & 63, rq = threadIdx.x >> 6;
    #pragma unroll
    for (int i = 0; i < 16; ++i) {
        int r = rq + 4 * i;
        float sc = dvec ? rsqrtf(dvec[k0 + r]) : 1.0f;
        tile[r][c] = in[(size_t)(k0 + r) * N + n0 + c] * sc;
    }
    __syncthreads();
    #pragma unroll
    for (int i = 0; i < 16; ++i) {
        int r = rq + 4 * i;
        int cc = swz ? (c ^ ((r & 7) << 3)) : c;
        out[(size_t)(n0 + r) * K + k0 + cc] = f2bf(tile[c][r]);
    }
}

// ---- K1: materialize A (swizzled bf16) + degree d[i] (unchanged from r12) ----
__global__ __launch_bounds__(512, 4) void k_gen_adj(const unsigned short* __restrict__ bbn_h,
                                                    const unsigned short* __restrict__ bbn_swz,
                                                    const float* __restrict__ s,
                                                    unsigned short* __restrict__ A_swz,
                                                    float* __restrict__ dd) {
    int bx = blockIdx.x;
    int it = bx >> 2, jq = bx & 3;
    int i0 = it * 64, jbase = jq * 2048;

    int tid = threadIdx.x;
    int w = tid >> 6, l = tid & 63, g = l >> 4, c = l & 15;
    int gi = w & 3, gj2 = w >> 2;

    const unsigned short* ap = bbn_h + (i0 + gi * 16 + c) * 64;
    short8 ga0 = ld8(ap), ga1 = ld8(ap + 32);
    float si = s[i0 + gi * 16 + c];

    __shared__ unsigned char AjldsF[3 * 8192];
    __shared__ unsigned char OutldsF[2 * 8192];
    __shared__ float sLDS[2048];

    const unsigned short* ajbase = bbn_swz + (jbase + w * 8 + (l >> 3)) * 64 + (l & 7) * 8;
    const int ajdst = w * 1024;

    const int sw = (c & 7) << 4;
    const int gj0 = gj2 * 2, gj1 = gj2 * 2 + 1;
    const int bo00 = (gj0 * 16 + c) * 128 + ((g * 16) ^ sw);
    const int bo01 = (gj0 * 16 + c) * 128 + ((64 + g * 16) ^ sw);
    const int bo10 = (gj1 * 16 + c) * 128 + ((g * 16) ^ sw);
    const int bo11 = (gj1 * 16 + c) * 128 + ((64 + g * 16) ^ sw);
    const int wr0 = ((gi * 16 + c) * 128 + (gj0 * 16 + g * 4) * 2) ^ sw;
    const int wr1 = ((gi * 16 + c) * 128 + (gj1 * 16 + g * 4) * 2) ^ sw;

    float racc = 0.f;

#define GEN_TILE(T) do {                                                           \
    const unsigned char* aj = &AjldsF[((T) % 3) * 8192];                           \
    unsigned char* outp = &OutldsF[((T) & 1) * 8192];                              \
    _Pragma("unroll")                                                              \
    for (int p = 0; p < 2; ++p) {                                                  \
        short8 gb0 = *reinterpret_cast<const short8*>(&aj[p ? bo10 : bo00]);       \
        short8 gb1 = *reinterpret_cast<const short8*>(&aj[p ? bo11 : bo01]);       \
        f32x4 sj4 = *reinterpret_cast<const f32x4*>(                               \
            &sLDS[(T) * 64 + (p ? gj1 : gj0) * 16 + g * 4]);                       \
        f32x4 gf = {0.f, 0.f, 0.f, 0.f};                                           \
        gf = MFMA16(gb0, ga0, gf);                                                 \
        gf = MFMA16(gb1, ga1, gf);                                                 \
        float t0 = fmaf(2.f, gf[0], -(si + sj4[0]));                               \
        float t1 = fmaf(2.f, gf[1], -(si + sj4[1]));                               \
        float t2 = fmaf(2.f, gf[2], -(si + sj4[2]));                               \
        float t3 = fmaf(2.f, gf[3], -(si + sj4[3]));                               \
        float u0 = pow14(fmaxf(fmaf(fabsf(t0), -0.015625f, 1.f), 0.f));            \
        float u1 = pow14(fmaxf(fmaf(fabsf(t1), -0.015625f, 1.f), 0.f));            \
        float u2 = pow14(fmaxf(fmaf(fabsf(t2), -0.015625f, 1.f), 0.f));            \
        float u3 = pow14(fmaxf(fmaf(fabsf(t3), -0.015625f, 1.f), 0.f));            \
        racc += (u0 + u1) + (u2 + u3);                                             \
        unsigned short p0 = f2bf(u0), p1 = f2bf(u1), p2 = f2bf(u2), p3 = f2bf(u3); \
        *reinterpret_cast<uint2*>(&outp[p ? wr1 : wr0]) =                          \
            make_uint2((unsigned)p0 | ((unsigned)p1 << 16),                        \
                       (unsigned)p2 | ((unsigned)p3 << 16));                       \
    }                                                                              \
} while (0)

    gld16(s + jbase + w * 256 + l * 4, (unsigned char*)sLDS + w * 1024);
    gld16(ajbase, &AjldsF[ajdst]);
    gld16(ajbase + 4096, &AjldsF[8192 + ajdst]);
    asm volatile("s_waitcnt vmcnt(1) lgkmcnt(0)\ns_barrier" ::: "memory");

    for (int t = 0; t < 32; ++t) {
        if (t > 0) {
            int row = tid >> 3, seg = tid & 7;
            uint4 v = *reinterpret_cast<const uint4*>(&OutldsF[((t - 1) & 1) * 8192 + tid * 16]);
            *reinterpret_cast<uint4*>(A_swz + (size_t)(i0 + row) * 8192 + jbase + (t - 1) * 64 + seg * 8) = v;
        }
        int jt = (t + 2 < 32) ? t + 2 : 31;
        gld16(ajbase + jt * 4096, &AjldsF[((t + 2) % 3) * 8192 + ajdst]);
        GEN_TILE(t);
        if (t == 0) { asm volatile("s_waitcnt vmcnt(1) lgkmcnt(0)\ns_barrier" ::: "memory"); }
        else        { asm volatile("s_waitcnt vmcnt(2) lgkmcnt(0)\ns_barrier" ::: "memory"); }
    }
    {
        int row = tid >> 3, seg = tid & 7;
        uint4 v = *reinterpret_cast<const uint4*>(&OutldsF[(31 & 1) * 8192 + tid * 16]);
        *reinterpret_cast<uint4*>(A_swz + (size_t)(i0 + row) * 8192 + jbase + 31 * 64 + seg * 8) = v;
    }
#undef GEN_TILE

    racc += __shfl_xor(racc, 16);
    racc += __shfl_xor(racc, 32);
    if (g == 0) atomicAdd(&dd[i0 + gi * 16 + c], racc);
}

// ---- K3: split-K GEMM hpart[ks] = A_swz[:,ks] @ cbn_sT[:,ks]^T ---------------
// BM=BN=128, BK=64, Kslice=2048; 256 thr, 4 waves (2x2), 64x64/wave (16 MAC/B).
// Grid 1024 = 64 row x 4 col x 4 ks = 4 blocks/CU (32KB LDS single-buffered);
// m97 2-barrier structure — vmcnt(0) drain hidden by 3 co-resident blocks.
__global__ __launch_bounds__(256, 4) void k_spectral(const unsigned short* __restrict__ A_swz,
                                                     const unsigned short* __restrict__ cbn_sT,
                                                     float* __restrict__ hpart) {
    int bx = blockIdx.x;
    int combo = bx & 15, row = bx >> 4;
    int n0 = (combo & 3) * 128;
    int k0 = (combo >> 2) * 2048;
    int i0 = row * 128;

    int tid = threadIdx.x;
    int w = tid >> 6, l = tid & 63, g = l >> 4, c = l & 15;
    int wm = w >> 1, wn = w & 1;
    int lrow = l >> 3, lseg = l & 7;

    __shared__ unsigned char Alds[16384];
    __shared__ unsigned char Blds[16384];

    f32x4 acc[4][4] = {};

    const unsigned short* srcA = A_swz + (size_t)(i0 + w * 8 + lrow) * 8192 + k0 + lseg * 8;
    const unsigned short* srcB = cbn_sT + (size_t)(n0 + w * 8 + lrow) * 8192 + k0 + lseg * 8;
    const int sw = (c & 7) << 4;

    for (int t = 0; t < 32; ++t) {
        int jt = t * 64;
        #pragma unroll
        for (int q = 0; q < 4; ++q) {
            gld16(srcA + (size_t)(q * 32) * 8192 + jt, &Alds[(w * 8 + q * 32) * 128]);
            gld16(srcB + (size_t)(q * 32) * 8192 + jt, &Blds[(w * 8 + q * 32) * 128]);
        }
        asm volatile("s_waitcnt vmcnt(0) lgkmcnt(0)\ns_barrier" ::: "memory");

        short8 af[4][2], bf[2][4];
        #pragma unroll
        for (int mi = 0; mi < 4; ++mi)
            #pragma unroll
            for (int kk = 0; kk < 2; ++kk)
                af[mi][kk] = *reinterpret_cast<const short8*>(
                    &Alds[(wm * 64 + mi * 16 + c) * 128 + ((kk * 64 + g * 16) ^ sw)]);
        #pragma unroll
        for (int kk = 0; kk < 2; ++kk)
            #pragma unroll
            for (int nn = 0; nn < 4; ++nn)
                bf[kk][nn] = *reinterpret_cast<const short8*>(
                    &Blds[(wn * 64 + nn * 16 + c) * 128 + ((kk * 64 + g * 16) ^ sw)]);

        __builtin_amdgcn_s_setprio(1);
        #pragma unroll
        for (int kk = 0; kk < 2; ++kk)
            #pragma unroll
            for (int mi = 0; mi < 4; ++mi)
                #pragma unroll
                for (int nn = 0; nn < 4; ++nn)
                    acc[mi][nn] = MFMA16(af[mi][kk], bf[kk][nn], acc[mi][nn]);
        __builtin_amdgcn_s_setprio(0);
        asm volatile("s_waitcnt lgkmcnt(0)\ns_barrier" ::: "memory");
    }

    // epilogue: raw fp32 partial (dinv applied in k_reduce)
    float* hp = hpart + (size_t)(combo >> 2) * (8192 * 512);
    #pragma unroll
    for (int mi = 0; mi < 4; ++mi)
        #pragma unroll
        for (int r = 0; r < 4; ++r) {
            int orow = i0 + wm * 64 + mi * 16 + g * 4 + r;
            #pragma unroll
            for (int nn = 0; nn < 4; ++nn)
                hp[(size_t)orow * 512 + n0 + wn * 64 + nn * 16 + c] = acc[mi][nn][r];
        }
}

// ---- K3b: h = bf16( (Σ_ks hpart) * dinv_i ); 4096 blocks x 256 thr x 4 elems --
__global__ __launch_bounds__(256) void k_reduce(const float* __restrict__ hpart,
                                                const float* __restrict__ dd,
                                                unsigned short* __restrict__ h) {
    size_t idx = ((size_t)blockIdx.x * 256 + threadIdx.x) * 4;
    const size_t PS = (size_t)8192 * 512;
    f32x4 v0 = *reinterpret_cast<const f32x4*>(hpart + idx);
    f32x4 v1 = *reinterpret_cast<const f32x4*>(hpart + PS + idx);
    f32x4 v2 = *reinterpret_cast<const f32x4*>(hpart + 2 * PS + idx);
    f32x4 v3 = *reinterpret_cast<const f32x4*>(hpart + 3 * PS + idx);
    f32x4 sum = (v0 + v1) + (v2 + v3);
    float dinv = rsqrtf(dd[idx >> 9]);
    ushort4 o;
    o.x = f2bf(sum[0] * dinv);
    o.y = f2bf(sum[1] * dinv);
    o.z = f2bf(sum[2] * dinv);
    o.w = f2bf(sum[3] * dinv);
    *reinterpret_cast<ushort4*>(h + idx) = o;
}

// ---- K4: out = sigmoid(h @ W + b), fp32 out ----------------------------------
__global__ __launch_bounds__(512) void k_out(const unsigned short* __restrict__ h,
                                             const unsigned short* __restrict__ Wt,
                                             const float* __restrict__ b,
                                             float* __restrict__ out) {
    int bx = blockIdx.x;
    int i0 = (bx & 255) * 32, n0 = (bx >> 8) * 256;
    int tid = threadIdx.x;
    int w = tid >> 6, l = tid & 63, g = l >> 4, c = l & 15;
    int wm = w >> 2, wn = w & 3;

    float bb[4];
    #pragma unroll
    for (int nn = 0; nn < 4; ++nn) bb[nn] = b[n0 + wn * 64 + nn * 16 + c];

    f32x4 acc[4] = {};
    for (int k0 = 0; k0 < 512; k0 += 64) {
        short8 af[2];
        #pragma unroll
        for (int kk = 0; kk < 2; ++kk)
            af[kk] = ld8(h + (size_t)(i0 + wm * 16 + c) * 512 + k0 + kk * 32 + g * 8);
        #pragma unroll
        for (int kk = 0; kk < 2; ++kk)
            #pragma unroll
            for (int nn = 0; nn < 4; ++nn) {
                short8 bf = ld8(Wt + (size_t)(n0 + wn * 64 + nn * 16 + c) * 512 + k0 + kk * 32 + g * 8);
                acc[nn] = MFMA16(af[kk], bf, acc[nn]);
            }
    }
    #pragma unroll
    for (int r = 0; r < 4; ++r) {
        int row = i0 + wm * 16 + g * 4 + r;
        #pragma unroll
        for (int nn = 0; nn < 4; ++nn) {
            float z = acc[nn][r] + bb[nn];
            out[(size_t)row * 512 + n0 + wn * 64 + nn * 16 + c] = 1.f / (1.f + exp2f(-1.44269504f * z));
        }
    }
}

extern "C" void kernel_launch(void* const* d_in, const int* in_sizes, int n_in,
                              void* d_out, int out_size, void* d_ws, size_t ws_size,
                              hipStream_t stream) {
    const float* bbn = (const float*)d_in[0];   // [8192, 64]
    const float* cbn = (const float*)d_in[1];   // [8192, 512]
    const float* W   = (const float*)d_in[2];   // [512, 512]
    const float* b   = (const float*)d_in[3];   // [512]
    float* out = (float*)d_out;                 // [8192, 512] fp32

    char* ws = (char*)d_ws;
    unsigned short* bbn_h   = (unsigned short*)(ws);                    // 1 MB
    unsigned short* bbn_swz = (unsigned short*)(ws + (1u << 20));       // 1 MB
    float*          s       = (float*)(ws + (2u << 20));                // 32 KB
    float*          dd      = (float*)(ws + (2u << 20) + (1u << 15));   // 32 KB
    unsigned short* Wt      = (unsigned short*)(ws + (2u << 20) + (2u << 15));  // 512 KB
    unsigned short* cbn_sT  = (unsigned short*)(ws + (3u << 20));       // 8 MB (swizzled, dinv_j-scaled)
    unsigned short* hbuf    = (unsigned short*)(ws + (11u << 20));      // 8 MB
    unsigned short* A_swz   = (unsigned short*)(ws + (19u << 20));      // 128 MB (swizzled adjacency)
    float*          hpart   = (float*)(ws + (147u << 20));              // 64 MB (4x fp32 partials)

    k_prep_bbn<<<2048, 256, 0, stream>>>(bbn, bbn_h, bbn_swz, s);
    k_zero_d<<<8, 1024, 0, stream>>>(dd);
    k_transpose_scale<<<64, 256, 0, stream>>>(W, Wt, nullptr, 512, 512, 0);
    k_gen_adj<<<512, 512, 0, stream>>>(bbn_h, bbn_swz, s, A_swz, dd);
    k_transpose_scale<<<1024, 256, 0, stream>>>(cbn, cbn_sT, dd, 8192, 512, 1);
    k_spectral<<<1024, 256, 0, stream>>>(A_swz, cbn_sT, hpart);
    k_reduce<<<4096, 256, 0, stream>>>(hpart, dd, hbuf);
    k_out<<<512, 512, 0, stream>>>(hbuf, Wt, b, out);
}

// Round 15
// 200.756 us; speedup vs baseline: 1.5027x; 1.5027x over previous
//
#include <hip/hip_runtime.h>
#include <hip/hip_bf16.h>

typedef __attribute__((ext_vector_type(8))) short short8;
typedef __attribute__((ext_vector_type(4))) float f32x4;

#define MFMA16(a, b, c) __builtin_amdgcn_mfma_f32_16x16x32_bf16((a), (b), (c), 0, 0, 0)

__device__ __forceinline__ unsigned short f2bf(float x) {
    union { float f; unsigned int u; } v; v.f = x;
    unsigned int u = v.u;
    return (unsigned short)((u + 0x7FFFu + ((u >> 16) & 1u)) >> 16);
}

__device__ __forceinline__ float pow14(float x) {
    return exp2f(1.4f * log2f(x));
}

__device__ __forceinline__ short8 ld8(const unsigned short* p) {
    return *reinterpret_cast<const short8*>(p);
}

__device__ __forceinline__ void gld16(const void* src, const unsigned char* dst) {
    __builtin_amdgcn_global_load_lds(
        (const __attribute__((address_space(1))) void*)src,
        (__attribute__((address_space(3))) void*)dst, 16, 0, 0);
}

// ---- K0: bbn fp32 -> bf16 (plain + row-swizzled copy), row sums s[i] ---------
__global__ void k_prep_bbn(const float* __restrict__ bbn, unsigned short* __restrict__ bbn_h,
                           unsigned short* __restrict__ bbn_swz, float* __restrict__ s) {
    int row = blockIdx.x * 4 + (threadIdx.x >> 6);
    int lane = threadIdx.x & 63;
    float x = bbn[row * 64 + lane];
    unsigned short h = f2bf(x);
    bbn_h[row * 64 + lane] = h;
    bbn_swz[row * 64 + (lane ^ ((row & 7) << 3))] = h;
    float v = x;
    #pragma unroll
    for (int m = 1; m < 64; m <<= 1) v += __shfl_xor(v, m);
    if (lane == 0) s[row] = v;
}

__global__ void k_zero_d(float* __restrict__ dd) {
    dd[blockIdx.x * 1024 + threadIdx.x] = 0.f;
}

// ---- K0b/K2: transpose (+optional rsqrt(d) row scale, optional swizzle) ------
__global__ void k_transpose_scale(const float* __restrict__ in, unsigned short* __restrict__ out,
                                  const float* __restrict__ dvec, int K, int N, int swz) {
    __shared__ float tile[64][65];
    int tiles_k = K >> 6;
    int tk = blockIdx.x % tiles_k, tn = blockIdx.x / tiles_k;
    int k0 = tk * 64, n0 = tn * 64;
    int c = threadIdx.x & 63, rq = threadIdx.x >> 6;
    #pragma unroll
    for (int i = 0; i < 16; ++i) {
        int r = rq + 4 * i;
        float sc = dvec ? rsqrtf(dvec[k0 + r]) : 1.0f;
        tile[r][c] = in[(size_t)(k0 + r) * N + n0 + c] * sc;
    }
    __syncthreads();
    #pragma unroll
    for (int i = 0; i < 16; ++i) {
        int r = rq + 4 * i;
        int cc = swz ? (c ^ ((r & 7) << 3)) : c;
        out[(size_t)(n0 + r) * K + k0 + cc] = f2bf(tile[c][r]);
    }
}

// ---- K1: materialize A (swizzled bf16) + degree d[i] (unchanged from r12) ----
__global__ __launch_bounds__(512, 4) void k_gen_adj(const unsigned short* __restrict__ bbn_h,
                                                    const unsigned short* __restrict__ bbn_swz,
                                                    const float* __restrict__ s,
                                                    unsigned short* __restrict__ A_swz,
                                                    float* __restrict__ dd) {
    int bx = blockIdx.x;
    int it = bx >> 2, jq = bx & 3;
    int i0 = it * 64, jbase = jq * 2048;

    int tid = threadIdx.x;
    int w = tid >> 6, l = tid & 63, g = l >> 4, c = l & 15;
    int gi = w & 3, gj2 = w >> 2;

    const unsigned short* ap = bbn_h + (i0 + gi * 16 + c) * 64;
    short8 ga0 = ld8(ap), ga1 = ld8(ap + 32);
    float si = s[i0 + gi * 16 + c];

    __shared__ unsigned char AjldsF[3 * 8192];
    __shared__ unsigned char OutldsF[2 * 8192];
    __shared__ float sLDS[2048];

    const unsigned short* ajbase = bbn_swz + (jbase + w * 8 + (l >> 3)) * 64 + (l & 7) * 8;
    const int ajdst = w * 1024;

    const int sw = (c & 7) << 4;
    const int gj0 = gj2 * 2, gj1 = gj2 * 2 + 1;
    const int bo00 = (gj0 * 16 + c) * 128 + ((g * 16) ^ sw);
    const int bo01 = (gj0 * 16 + c) * 128 + ((64 + g * 16) ^ sw);
    const int bo10 = (gj1 * 16 + c) * 128 + ((g * 16) ^ sw);
    const int bo11 = (gj1 * 16 + c) * 128 + ((64 + g * 16) ^ sw);
    const int wr0 = ((gi * 16 + c) * 128 + (gj0 * 16 + g * 4) * 2) ^ sw;
    const int wr1 = ((gi * 16 + c) * 128 + (gj1 * 16 + g * 4) * 2) ^ sw;

    float racc = 0.f;

#define GEN_TILE(T) do {                                                           \
    const unsigned char* aj = &AjldsF[((T) % 3) * 8192];                           \
    unsigned char* outp = &OutldsF[((T) & 1) * 8192];                              \
    _Pragma("unroll")                                                              \
    for (int p = 0; p < 2; ++p) {                                                  \
        short8 gb0 = *reinterpret_cast<const short8*>(&aj[p ? bo10 : bo00]);       \
        short8 gb1 = *reinterpret_cast<const short8*>(&aj[p ? bo11 : bo01]);       \
        f32x4 sj4 = *reinterpret_cast<const f32x4*>(                               \
            &sLDS[(T) * 64 + (p ? gj1 : gj0) * 16 + g * 4]);                       \
        f32x4 gf = {0.f, 0.f, 0.f, 0.f};                                           \
        gf = MFMA16(gb0, ga0, gf);                                                 \
        gf = MFMA16(gb1, ga1, gf);                                                 \
        float t0 = fmaf(2.f, gf[0], -(si + sj4[0]));                               \
        float t1 = fmaf(2.f, gf[1], -(si + sj4[1]));                               \
        float t2 = fmaf(2.f, gf[2], -(si + sj4[2]));                               \
        float t3 = fmaf(2.f, gf[3], -(si + sj4[3]));                               \
        float u0 = pow14(fmaxf(fmaf(fabsf(t0), -0.015625f, 1.f), 0.f));            \
        float u1 = pow14(fmaxf(fmaf(fabsf(t1), -0.015625f, 1.f), 0.f));            \
        float u2 = pow14(fmaxf(fmaf(fabsf(t2), -0.015625f, 1.f), 0.f));            \
        float u3 = pow14(fmaxf(fmaf(fabsf(t3), -0.015625f, 1.f), 0.f));            \
        racc += (u0 + u1) + (u2 + u3);                                             \
        unsigned short p0 = f2bf(u0), p1 = f2bf(u1), p2 = f2bf(u2), p3 = f2bf(u3); \
        *reinterpret_cast<uint2*>(&outp[p ? wr1 : wr0]) =                          \
            make_uint2((unsigned)p0 | ((unsigned)p1 << 16),                        \
                       (unsigned)p2 | ((unsigned)p3 << 16));                       \
    }                                                                              \
} while (0)

    gld16(s + jbase + w * 256 + l * 4, (unsigned char*)sLDS + w * 1024);
    gld16(ajbase, &AjldsF[ajdst]);
    gld16(ajbase + 4096, &AjldsF[8192 + ajdst]);
    asm volatile("s_waitcnt vmcnt(1) lgkmcnt(0)\ns_barrier" ::: "memory");

    for (int t = 0; t < 32; ++t) {
        if (t > 0) {
            int row = tid >> 3, seg = tid & 7;
            uint4 v = *reinterpret_cast<const uint4*>(&OutldsF[((t - 1) & 1) * 8192 + tid * 16]);
            *reinterpret_cast<uint4*>(A_swz + (size_t)(i0 + row) * 8192 + jbase + (t - 1) * 64 + seg * 8) = v;
        }
        int jt = (t + 2 < 32) ? t + 2 : 31;
        gld16(ajbase + jt * 4096, &AjldsF[((t + 2) % 3) * 8192 + ajdst]);
        GEN_TILE(t);
        if (t == 0) { asm volatile("s_waitcnt vmcnt(1) lgkmcnt(0)\ns_barrier" ::: "memory"); }
        else        { asm volatile("s_waitcnt vmcnt(2) lgkmcnt(0)\ns_barrier" ::: "memory"); }
    }
    {
        int row = tid >> 3, seg = tid & 7;
        uint4 v = *reinterpret_cast<const uint4*>(&OutldsF[(31 & 1) * 8192 + tid * 16]);
        *reinterpret_cast<uint4*>(A_swz + (size_t)(i0 + row) * 8192 + jbase + 31 * 64 + seg * 8) = v;
    }
#undef GEN_TILE

    racc += __shfl_xor(racc, 16);
    racc += __shfl_xor(racc, 32);
    if (g == 0) atomicAdd(&dd[i0 + gi * 16 + c], racc);
}

// ---- K3: split-K GEMM, block-contiguous fp32 partials -------------------------
// BM=64, BN=256, BK=64, Ksplit=2; 512 thr, 8 waves (2x4), wave tile 32x64.
// Grid 512 = 128 row x 2 col x 2 ks = 2 blocks/CU (80KB LDS dbuf).
// bx = row*4 + col*2 + ks: the 4 blocks sharing an A row-strip dispatch
// adjacently -> A HBM-read ~once. Partials written block-contiguous (64KB per
// block) -> full-line writes, no RMW amplification (r14's 305MB WRITE bug).
__global__ __launch_bounds__(512, 4) void k_spectral(const unsigned short* __restrict__ A_swz,
                                                     const unsigned short* __restrict__ cbn_sT,
                                                     float* __restrict__ hpart) {
    int bx = blockIdx.x;
    int row = bx >> 2, col = (bx >> 1) & 1, ks = bx & 1;
    int i0 = row * 64, n0 = col * 256, k0 = ks * 4096;

    int tid = threadIdx.x;
    int w = tid >> 6, l = tid & 63, g = l >> 4, c = l & 15;
    int wm = w >> 2, wn = w & 3;     // wave tile: rows wm*32, cols wn*64
    int lrow = l >> 3, lseg = l & 7;

    __shared__ unsigned char Alds[2][8192];
    __shared__ unsigned char Blds[2][32768];

    f32x4 acc[2][4] = {};

    const unsigned short* srcA = A_swz + (size_t)(i0 + w * 8 + lrow) * 8192 + k0 + lseg * 8;
    const unsigned short* srcB = cbn_sT + (size_t)(n0 + w * 32 + lrow) * 8192 + k0 + lseg * 8;
    const int sw = (c & 7) << 4;

#define STAGE(BUF, JT) do {                                                        \
    gld16(srcA + (JT), &Alds[BUF][w * 1024]);                                      \
    _Pragma("unroll")                                                              \
    for (int q = 0; q < 4; ++q)                                                    \
        gld16(srcB + (size_t)(q * 8) * 8192 + (JT),                                \
              &Blds[BUF][(w * 32 + q * 8) * 128]);                                 \
} while (0)

    STAGE(0, 0);
    asm volatile("s_waitcnt vmcnt(0) lgkmcnt(0)\ns_barrier" ::: "memory");

    for (int t = 0; t < 64; ++t) {
        int cur = t & 1, nxt = cur ^ 1;
        if (t < 63) STAGE(nxt, (t + 1) * 64);

        short8 af[2][2], bf[2][4];
        #pragma unroll
        for (int mi = 0; mi < 2; ++mi)
            #pragma unroll
            for (int kk = 0; kk < 2; ++kk)
                af[mi][kk] = *reinterpret_cast<const short8*>(
                    &Alds[cur][(wm * 32 + mi * 16 + c) * 128 + ((kk * 64 + g * 16) ^ sw)]);
        #pragma unroll
        for (int kk = 0; kk < 2; ++kk)
            #pragma unroll
            for (int nn = 0; nn < 4; ++nn)
                bf[kk][nn] = *reinterpret_cast<const short8*>(
                    &Blds[cur][(wn * 64 + nn * 16 + c) * 128 + ((kk * 64 + g * 16) ^ sw)]);

        __builtin_amdgcn_s_setprio(1);
        #pragma unroll
        for (int kk = 0; kk < 2; ++kk)
            #pragma unroll
            for (int nn = 0; nn < 4; ++nn) {
                acc[0][nn] = MFMA16(af[0][kk], bf[kk][nn], acc[0][nn]);
                acc[1][nn] = MFMA16(af[1][kk], bf[kk][nn], acc[1][nn]);
            }
        __builtin_amdgcn_s_setprio(0);
        asm volatile("s_waitcnt vmcnt(0) lgkmcnt(0)\ns_barrier" ::: "memory");
    }
#undef STAGE

    // epilogue: block-contiguous 64KB partial tile (64 rows x 256 cols fp32)
    float* hp = hpart + (size_t)bx * 16384;
    #pragma unroll
    for (int mi = 0; mi < 2; ++mi)
        #pragma unroll
        for (int r = 0; r < 4; ++r) {
            int lr = wm * 32 + mi * 16 + g * 4 + r;
            #pragma unroll
            for (int nn = 0; nn < 4; ++nn)
                hp[lr * 256 + wn * 64 + nn * 16 + c] = acc[mi][nn][r];
        }
}

// ---- K3b: h = bf16( (Σ_ks hpart) * dinv_i ); 4096 blocks x 256 thr x 4 elems --
__global__ __launch_bounds__(256) void k_reduce(const float* __restrict__ hpart,
                                                const float* __restrict__ dd,
                                                unsigned short* __restrict__ h) {
    size_t flat = ((size_t)blockIdx.x * 256 + threadIdx.x) * 4;
    int i = (int)(flat >> 9), n = (int)(flat & 511);
    int row = i >> 6, col = n >> 8;
    int local = (i & 63) * 256 + (n & 255);
    size_t base = (size_t)(row * 4 + col * 2) * 16384;
    f32x4 v0 = *reinterpret_cast<const f32x4*>(hpart + base + local);
    f32x4 v1 = *reinterpret_cast<const f32x4*>(hpart + base + 16384 + local);
    f32x4 sum = v0 + v1;
    float dinv = rsqrtf(dd[i]);
    ushort4 o;
    o.x = f2bf(sum[0] * dinv);
    o.y = f2bf(sum[1] * dinv);
    o.z = f2bf(sum[2] * dinv);
    o.w = f2bf(sum[3] * dinv);
    *reinterpret_cast<ushort4*>(h + flat) = o;
}

// ---- K4: out = sigmoid(h @ W + b), fp32 out ----------------------------------
__global__ __launch_bounds__(512) void k_out(const unsigned short* __restrict__ h,
                                             const unsigned short* __restrict__ Wt,
                                             const float* __restrict__ b,
                                             float* __restrict__ out) {
    int bx = blockIdx.x;
    int i0 = (bx & 255) * 32, n0 = (bx >> 8) * 256;
    int tid = threadIdx.x;
    int w = tid >> 6, l = tid & 63, g = l >> 4, c = l & 15;
    int wm = w >> 2, wn = w & 3;

    float bb[4];
    #pragma unroll
    for (int nn = 0; nn < 4; ++nn) bb[nn] = b[n0 + wn * 64 + nn * 16 + c];

    f32x4 acc[4] = {};
    for (int k0 = 0; k0 < 512; k0 += 64) {
        short8 af[2];
        #pragma unroll
        for (int kk = 0; kk < 2; ++kk)
            af[kk] = ld8(h + (size_t)(i0 + wm * 16 + c) * 512 + k0 + kk * 32 + g * 8);
        #pragma unroll
        for (int kk = 0; kk < 2; ++kk)
            #pragma unroll
            for (int nn = 0; nn < 4; ++nn) {
                short8 bf = ld8(Wt + (size_t)(n0 + wn * 64 + nn * 16 + c) * 512 + k0 + kk * 32 + g * 8);
                acc[nn] = MFMA16(af[kk], bf, acc[nn]);
            }
    }
    #pragma unroll
    for (int r = 0; r < 4; ++r) {
        int row = i0 + wm * 16 + g * 4 + r;
        #pragma unroll
        for (int nn = 0; nn < 4; ++nn) {
            float z = acc[nn][r] + bb[nn];
            out[(size_t)row * 512 + n0 + wn * 64 + nn * 16 + c] = 1.f / (1.f + exp2f(-1.44269504f * z));
        }
    }
}

extern "C" void kernel_launch(void* const* d_in, const int* in_sizes, int n_in,
                              void* d_out, int out_size, void* d_ws, size_t ws_size,
                              hipStream_t stream) {
    const float* bbn = (const float*)d_in[0];   // [8192, 64]
    const float* cbn = (const float*)d_in[1];   // [8192, 512]
    const float* W   = (const float*)d_in[2];   // [512, 512]
    const float* b   = (const float*)d_in[3];   // [512]
    float* out = (float*)d_out;                 // [8192, 512] fp32

    char* ws = (char*)d_ws;
    unsigned short* bbn_h   = (unsigned short*)(ws);                    // 1 MB
    unsigned short* bbn_swz = (unsigned short*)(ws + (1u << 20));       // 1 MB
    float*          s       = (float*)(ws + (2u << 20));                // 32 KB
    float*          dd      = (float*)(ws + (2u << 20) + (1u << 15));   // 32 KB
    unsigned short* Wt      = (unsigned short*)(ws + (2u << 20) + (2u << 15));  // 512 KB
    unsigned short* cbn_sT  = (unsigned short*)(ws + (3u << 20));       // 8 MB (swizzled, dinv_j-scaled)
    unsigned short* hbuf    = (unsigned short*)(ws + (11u << 20));      // 8 MB
    unsigned short* A_swz   = (unsigned short*)(ws + (19u << 20));      // 128 MB (swizzled adjacency)
    float*          hpart   = (float*)(ws + (147u << 20));              // 32 MB (block-contiguous partials)

    k_prep_bbn<<<2048, 256, 0, stream>>>(bbn, bbn_h, bbn_swz, s);
    k_zero_d<<<8, 1024, 0, stream>>>(dd);
    k_transpose_scale<<<64, 256, 0, stream>>>(W, Wt, nullptr, 512, 512, 0);
    k_gen_adj<<<512, 512, 0, stream>>>(bbn_h, bbn_swz, s, A_swz, dd);
    k_transpose_scale<<<1024, 256, 0, stream>>>(cbn, cbn_sT, dd, 8192, 512, 1);
    k_spectral<<<512, 512, 0, stream>>>(A_swz, cbn_sT, hpart);
    k_reduce<<<4096, 256, 0, stream>>>(hpart, dd, hbuf);
    k_out<<<512, 512, 0, stream>>>(hbuf, Wt, b, out);
}

// Round 16
// 195.266 us; speedup vs baseline: 1.5450x; 1.0281x over previous
//
#include <hip/hip_runtime.h>
#include <hip/hip_bf16.h>

typedef __attribute__((ext_vector_type(8))) short short8;
typedef __attribute__((ext_vector_type(4))) float f32x4;

#define MFMA16(a, b, c) __builtin_amdgcn_mfma_f32_16x16x32_bf16((a), (b), (c), 0, 0, 0)

__device__ __forceinline__ unsigned short f2bf(float x) {
    union { float f; unsigned int u; } v; v.f = x;
    unsigned int u = v.u;
    return (unsigned short)((u + 0x7FFFu + ((u >> 16) & 1u)) >> 16);
}

__device__ __forceinline__ float pow14(float x) {
    return exp2f(1.4f * log2f(x));
}

__device__ __forceinline__ short8 ld8(const unsigned short* p) {
    return *reinterpret_cast<const short8*>(p);
}

__device__ __forceinline__ void gld16(const void* src, const unsigned char* dst) {
    __builtin_amdgcn_global_load_lds(
        (const __attribute__((address_space(1))) void*)src,
        (__attribute__((address_space(3))) void*)dst, 16, 0, 0);
}

// ---- K0: bbn fp32 -> bf16 (plain + row-swizzled copy), row sums s[i] ---------
__global__ void k_prep_bbn(const float* __restrict__ bbn, unsigned short* __restrict__ bbn_h,
                           unsigned short* __restrict__ bbn_swz, float* __restrict__ s) {
    int row = blockIdx.x * 4 + (threadIdx.x >> 6);
    int lane = threadIdx.x & 63;
    float x = bbn[row * 64 + lane];
    unsigned short h = f2bf(x);
    bbn_h[row * 64 + lane] = h;
    bbn_swz[row * 64 + (lane ^ ((row & 7) << 3))] = h;
    float v = x;
    #pragma unroll
    for (int m = 1; m < 64; m <<= 1) v += __shfl_xor(v, m);
    if (lane == 0) s[row] = v;
}

__global__ void k_zero_d(float* __restrict__ dd) {
    dd[blockIdx.x * 1024 + threadIdx.x] = 0.f;
}

// ---- K0b/K2: transpose (+optional rsqrt(d) row scale, optional swizzle) ------
__global__ void k_transpose_scale(const float* __restrict__ in, unsigned short* __restrict__ out,
                                  const float* __restrict__ dvec, int K, int N, int swz) {
    __shared__ float tile[64][65];
    int tiles_k = K >> 6;
    int tk = blockIdx.x % tiles_k, tn = blockIdx.x / tiles_k;
    int k0 = tk * 64, n0 = tn * 64;
    int c = threadIdx.x & 63, rq = threadIdx.x >> 6;
    #pragma unroll
    for (int i = 0; i < 16; ++i) {
        int r = rq + 4 * i;
        float sc = dvec ? rsqrtf(dvec[k0 + r]) : 1.0f;
        tile[r][c] = in[(size_t)(k0 + r) * N + n0 + c] * sc;
    }
    __syncthreads();
    #pragma unroll
    for (int i = 0; i < 16; ++i) {
        int r = rq + 4 * i;
        int cc = swz ? (c ^ ((r & 7) << 3)) : c;
        out[(size_t)(n0 + r) * K + k0 + cc] = f2bf(tile[c][r]);
    }
}

// ---- K1: materialize A (swizzled bf16) + degree d[i] --------------------------
// 512 blocks = 128 i-tiles x 4 j-quarters; 512 threads, 8 waves, 2 blocks/CU.
// UNROLL-2: two 64-col tiles per barrier period (16 periods, half the barriers).
// 4-deep Aj buffer; glds issued BEFORE writeback stores so vmcnt(2) retires the
// glds for next period while leaving this period's stores in flight.
__global__ __launch_bounds__(512, 4) void k_gen_adj(const unsigned short* __restrict__ bbn_h,
                                                    const unsigned short* __restrict__ bbn_swz,
                                                    const float* __restrict__ s,
                                                    unsigned short* __restrict__ A_swz,
                                                    float* __restrict__ dd) {
    int bx = blockIdx.x;
    int it = bx >> 2, jq = bx & 3;
    int i0 = it * 64, jbase = jq * 2048;

    int tid = threadIdx.x;
    int w = tid >> 6, l = tid & 63, g = l >> 4, c = l & 15;
    int gi = w & 3, gj2 = w >> 2;

    const unsigned short* ap = bbn_h + (i0 + gi * 16 + c) * 64;
    short8 ga0 = ld8(ap), ga1 = ld8(ap + 32);
    float si = s[i0 + gi * 16 + c];

    __shared__ unsigned char AjldsF[4 * 8192];
    __shared__ unsigned char OutldsF[2 * 8192];
    __shared__ float sLDS[2048];

    const unsigned short* ajbase = bbn_swz + (jbase + w * 8 + (l >> 3)) * 64 + (l & 7) * 8;
    const int ajdst = w * 1024;

    const int sw = (c & 7) << 4;
    const int gj0 = gj2 * 2, gj1 = gj2 * 2 + 1;
    const int bo00 = (gj0 * 16 + c) * 128 + ((g * 16) ^ sw);
    const int bo01 = (gj0 * 16 + c) * 128 + ((64 + g * 16) ^ sw);
    const int bo10 = (gj1 * 16 + c) * 128 + ((g * 16) ^ sw);
    const int bo11 = (gj1 * 16 + c) * 128 + ((64 + g * 16) ^ sw);
    const int wr0 = ((gi * 16 + c) * 128 + (gj0 * 16 + g * 4) * 2) ^ sw;
    const int wr1 = ((gi * 16 + c) * 128 + (gj1 * 16 + g * 4) * 2) ^ sw;

    float racc = 0.f;

#define GEN_TILE(T, OB) do {                                                       \
    const unsigned char* aj = &AjldsF[((T) & 3) * 8192];                           \
    unsigned char* outp = &OutldsF[(OB) * 8192];                                   \
    _Pragma("unroll")                                                              \
    for (int p = 0; p < 2; ++p) {                                                  \
        short8 gb0 = *reinterpret_cast<const short8*>(&aj[p ? bo10 : bo00]);       \
        short8 gb1 = *reinterpret_cast<const short8*>(&aj[p ? bo11 : bo01]);       \
        f32x4 sj4 = *reinterpret_cast<const f32x4*>(                               \
            &sLDS[(T) * 64 + (p ? gj1 : gj0) * 16 + g * 4]);                       \
        f32x4 gf = {0.f, 0.f, 0.f, 0.f};                                           \
        gf = MFMA16(gb0, ga0, gf);                                                 \
        gf = MFMA16(gb1, ga1, gf);                                                 \
        float t0 = fmaf(2.f, gf[0], -(si + sj4[0]));                               \
        float t1 = fmaf(2.f, gf[1], -(si + sj4[1]));                               \
        float t2 = fmaf(2.f, gf[2], -(si + sj4[2]));                               \
        float t3 = fmaf(2.f, gf[3], -(si + sj4[3]));                               \
        float u0 = pow14(fmaxf(fmaf(fabsf(t0), -0.015625f, 1.f), 0.f));            \
        float u1 = pow14(fmaxf(fmaf(fabsf(t1), -0.015625f, 1.f), 0.f));            \
        float u2 = pow14(fmaxf(fmaf(fabsf(t2), -0.015625f, 1.f), 0.f));            \
        float u3 = pow14(fmaxf(fmaf(fabsf(t3), -0.015625f, 1.f), 0.f));            \
        racc += (u0 + u1) + (u2 + u3);                                             \
        unsigned short p0 = f2bf(u0), p1 = f2bf(u1), p2 = f2bf(u2), p3 = f2bf(u3); \
        *reinterpret_cast<uint2*>(&outp[p ? wr1 : wr0]) =                          \
            make_uint2((unsigned)p0 | ((unsigned)p1 << 16),                        \
                       (unsigned)p2 | ((unsigned)p3 << 16));                       \
    }                                                                              \
} while (0)

#define WB(T, OB) do {                                                             \
    int row_ = tid >> 3, seg_ = tid & 7;                                           \
    uint4 v_ = *reinterpret_cast<const uint4*>(&OutldsF[(OB) * 8192 + tid * 16]);  \
    *reinterpret_cast<uint4*>(A_swz + (size_t)(i0 + row_) * 8192 + jbase + (T) * 64 + seg_ * 8) = v_; \
} while (0)

    // prologue: s-quarter + Aj tiles 0,1 -> slots 0,1
    gld16(s + jbase + w * 256 + l * 4, (unsigned char*)sLDS + w * 1024);
    gld16(ajbase, &AjldsF[ajdst]);
    gld16(ajbase + 4096, &AjldsF[8192 + ajdst]);
    asm volatile("s_waitcnt vmcnt(0) lgkmcnt(0)\ns_barrier" ::: "memory");

    for (int u = 0; u < 16; ++u) {
        // stage tiles 2u+2, 2u+3 (consumed next period) — glds FIRST
        int t2 = (2 * u + 2 < 32) ? 2 * u + 2 : 30;
        int t3 = (2 * u + 3 < 32) ? 2 * u + 3 : 31;
        gld16(ajbase + t2 * 4096, &AjldsF[((2 * u + 2) & 3) * 8192 + ajdst]);
        gld16(ajbase + t3 * 4096, &AjldsF[((2 * u + 3) & 3) * 8192 + ajdst]);
        // writeback previous period's tiles (stores after glds)
        if (u > 0) { WB(2 * u - 2, 0); WB(2 * u - 1, 1); }
        GEN_TILE(2 * u, 0);
        GEN_TILE(2 * u + 1, 1);
        // retire the 2 glds (next period's data); stores may linger
        asm volatile("s_waitcnt vmcnt(2) lgkmcnt(0)\ns_barrier" ::: "memory");
    }
    WB(30, 0);
    WB(31, 1);
#undef GEN_TILE
#undef WB

    racc += __shfl_xor(racc, 16);
    racc += __shfl_xor(racc, 32);
    if (g == 0) atomicAdd(&dd[i0 + gi * 16 + c], racc);
}

// ---- K3: split-K GEMM, BM=64 x BN=512 (full width), Ksplit=4 ------------------
// 512 blocks = 128 row x 4 ks = 2 blocks/CU; 512 thr, 8 waves, 64x64/wave
// (16 MAC/LDS-byte). A read exactly once (no col split). Single-buffered
// 72KB LDS, m97 2-barrier loop — co-resident block hides the vmcnt(0) drain.
__global__ __launch_bounds__(512, 4) void k_spectral(const unsigned short* __restrict__ A_swz,
                                                     const unsigned short* __restrict__ cbn_sT,
                                                     float* __restrict__ hpart) {
    int bx = blockIdx.x;
    int row = bx >> 2, ks = bx & 3;
    int i0 = row * 64, k0 = ks * 2048;

    int tid = threadIdx.x;
    int w = tid >> 6, l = tid & 63, g = l >> 4, c = l & 15;
    int lrow = l >> 3, lseg = l & 7;

    __shared__ unsigned char Alds[8192];    // 64 rows x 128B
    __shared__ unsigned char Blds[65536];   // 512 rows x 128B

    f32x4 acc[4][4] = {};

    const unsigned short* srcA = A_swz + (size_t)(i0 + w * 8 + lrow) * 8192 + k0 + lseg * 8;
    const unsigned short* srcB = cbn_sT + (size_t)(w * 8 + lrow) * 8192 + k0 + lseg * 8;
    const int sw = (c & 7) << 4;

    for (int t = 0; t < 32; ++t) {
        int jt = t * 64;
        gld16(srcA + jt, &Alds[w * 1024]);
        #pragma unroll
        for (int q = 0; q < 8; ++q)
            gld16(srcB + (size_t)(q * 64) * 8192 + jt, &Blds[(q * 64 + w * 8) * 128]);
        asm volatile("s_waitcnt vmcnt(0) lgkmcnt(0)\ns_barrier" ::: "memory");

        #pragma unroll
        for (int kk = 0; kk < 2; ++kk) {
            short8 af[4], bf[4];
            #pragma unroll
            for (int mi = 0; mi < 4; ++mi)
                af[mi] = *reinterpret_cast<const short8*>(
                    &Alds[(mi * 16 + c) * 128 + ((kk * 64 + g * 16) ^ sw)]);
            #pragma unroll
            for (int nn = 0; nn < 4; ++nn)
                bf[nn] = *reinterpret_cast<const short8*>(
                    &Blds[(w * 64 + nn * 16 + c) * 128 + ((kk * 64 + g * 16) ^ sw)]);
            __builtin_amdgcn_s_setprio(1);
            #pragma unroll
            for (int mi = 0; mi < 4; ++mi)
                #pragma unroll
                for (int nn = 0; nn < 4; ++nn)
                    acc[mi][nn] = MFMA16(af[mi], bf[nn], acc[mi][nn]);
            __builtin_amdgcn_s_setprio(0);
        }
        asm volatile("s_waitcnt lgkmcnt(0)\ns_barrier" ::: "memory");
    }

    // epilogue: block-contiguous 128KB fp32 partial tile (64 rows x 512 cols)
    float* hp = hpart + (size_t)bx * 32768;
    #pragma unroll
    for (int mi = 0; mi < 4; ++mi)
        #pragma unroll
        for (int r = 0; r < 4; ++r) {
            int lr = mi * 16 + g * 4 + r;
            #pragma unroll
            for (int nn = 0; nn < 4; ++nn)
                hp[lr * 512 + w * 64 + nn * 16 + c] = acc[mi][nn][r];
        }
}

// ---- K3b: h = bf16( (Σ_ks hpart) * dinv_i ); 4096 blocks x 256 thr x 4 elems --
__global__ __launch_bounds__(256) void k_reduce(const float* __restrict__ hpart,
                                                const float* __restrict__ dd,
                                                unsigned short* __restrict__ h) {
    size_t flat = ((size_t)blockIdx.x * 256 + threadIdx.x) * 4;
    int i = (int)(flat >> 9), n = (int)(flat & 511);
    int row = i >> 6;
    int local = (i & 63) * 512 + n;
    size_t base = (size_t)(row * 4) * 32768;
    f32x4 v0 = *reinterpret_cast<const f32x4*>(hpart + base + local);
    f32x4 v1 = *reinterpret_cast<const f32x4*>(hpart + base + 32768 + local);
    f32x4 v2 = *reinterpret_cast<const f32x4*>(hpart + base + 2 * 32768 + local);
    f32x4 v3 = *reinterpret_cast<const f32x4*>(hpart + base + 3 * 32768 + local);
    f32x4 sum = (v0 + v1) + (v2 + v3);
    float dinv = rsqrtf(dd[i]);
    ushort4 o;
    o.x = f2bf(sum[0] * dinv);
    o.y = f2bf(sum[1] * dinv);
    o.z = f2bf(sum[2] * dinv);
    o.w = f2bf(sum[3] * dinv);
    *reinterpret_cast<ushort4*>(h + flat) = o;
}

// ---- K4: out = sigmoid(h @ W + b), fp32 out ----------------------------------
__global__ __launch_bounds__(512) void k_out(const unsigned short* __restrict__ h,
                                             const unsigned short* __restrict__ Wt,
                                             const float* __restrict__ b,
                                             float* __restrict__ out) {
    int bx = blockIdx.x;
    int i0 = (bx & 255) * 32, n0 = (bx >> 8) * 256;
    int tid = threadIdx.x;
    int w = tid >> 6, l = tid & 63, g = l >> 4, c = l & 15;
    int wm = w >> 2, wn = w & 3;

    float bb[4];
    #pragma unroll
    for (int nn = 0; nn < 4; ++nn) bb[nn] = b[n0 + wn * 64 + nn * 16 + c];

    f32x4 acc[4] = {};
    for (int k0 = 0; k0 < 512; k0 += 64) {
        short8 af[2];
        #pragma unroll
        for (int kk = 0; kk < 2; ++kk)
            af[kk] = ld8(h + (size_t)(i0 + wm * 16 + c) * 512 + k0 + kk * 32 + g * 8);
        #pragma unroll
        for (int kk = 0; kk < 2; ++kk)
            #pragma unroll
            for (int nn = 0; nn < 4; ++nn) {
                short8 bf = ld8(Wt + (size_t)(n0 + wn * 64 + nn * 16 + c) * 512 + k0 + kk * 32 + g * 8);
                acc[nn] = MFMA16(af[kk], bf, acc[nn]);
            }
    }
    #pragma unroll
    for (int r = 0; r < 4; ++r) {
        int row = i0 + wm * 16 + g * 4 + r;
        #pragma unroll
        for (int nn = 0; nn < 4; ++nn) {
            float z = acc[nn][r] + bb[nn];
            out[(size_t)row * 512 + n0 + wn * 64 + nn * 16 + c] = 1.f / (1.f + exp2f(-1.44269504f * z));
        }
    }
}

extern "C" void kernel_launch(void* const* d_in, const int* in_sizes, int n_in,
                              void* d_out, int out_size, void* d_ws, size_t ws_size,
                              hipStream_t stream) {
    const float* bbn = (const float*)d_in[0];   // [8192, 64]
    const float* cbn = (const float*)d_in[1];   // [8192, 512]
    const float* W   = (const float*)d_in[2];   // [512, 512]
    const float* b   = (const float*)d_in[3];   // [512]
    float* out = (float*)d_out;                 // [8192, 512] fp32

    char* ws = (char*)d_ws;
    unsigned short* bbn_h   = (unsigned short*)(ws);                    // 1 MB
    unsigned short* bbn_swz = (unsigned short*)(ws + (1u << 20));       // 1 MB
    float*          s       = (float*)(ws + (2u << 20));                // 32 KB
    float*          dd      = (float*)(ws + (2u << 20) + (1u << 15));   // 32 KB
    unsigned short* Wt      = (unsigned short*)(ws + (2u << 20) + (2u << 15));  // 512 KB
    unsigned short* cbn_sT  = (unsigned short*)(ws + (3u << 20));       // 8 MB (swizzled, dinv_j-scaled)
    unsigned short* hbuf    = (unsigned short*)(ws + (11u << 20));      // 8 MB
    unsigned short* A_swz   = (unsigned short*)(ws + (19u << 20));      // 128 MB (swizzled adjacency)
    float*          hpart   = (float*)(ws + (147u << 20));              // 64 MB (block-contiguous partials)

    k_prep_bbn<<<2048, 256, 0, stream>>>(bbn, bbn_h, bbn_swz, s);
    k_zero_d<<<8, 1024, 0, stream>>>(dd);
    k_transpose_scale<<<64, 256, 0, stream>>>(W, Wt, nullptr, 512, 512, 0);
    k_gen_adj<<<512, 512, 0, stream>>>(bbn_h, bbn_swz, s, A_swz, dd);
    k_transpose_scale<<<1024, 256, 0, stream>>>(cbn, cbn_sT, dd, 8192, 512, 1);
    k_spectral<<<512, 512, 0, stream>>>(A_swz, cbn_sT, hpart);
    k_reduce<<<4096, 256, 0, stream>>>(hpart, dd, hbuf);
    k_out<<<512, 512, 0, stream>>>(hbuf, Wt, b, out);
}